// Round 11
// baseline (2249.502 us; speedup 1.0000x reference)
//
#include <hip/hip_runtime.h>
#include <hip/hip_bf16.h>
#include <math.h>

// ---------------------------------------------------------------------------
// ImprovedDynamicCurvatureMLP on MI355X (gfx950)
//   x_bf,c = fused cast + per-row curvature
//   h_bf  = gemm256<tanh>(x_bf, W1^T)   [256^2, 8-wave, BK=32, 64KiB LDS ->
//   u_bf  = gemm256<sigmoid>(h_bf, W2^T) 2 blocks/CU cross-block overlap (m114)]
//   z_bf  = a(row)*h + b(row)*u         (Poincare layer = row scalars)
//   out   = gemm_out128(z_bf, Wout^T)   [128^2, N=1024 -> 256 blocks]
// ---------------------------------------------------------------------------

typedef __attribute__((ext_vector_type(8)))  __bf16 bf16x8;
typedef __attribute__((ext_vector_type(4)))  float  f32x4;
typedef __attribute__((ext_vector_type(8)))  unsigned short us8;

constexpr int BATCH = 4096;
constexpr int IND   = 4096;
constexpr int HIDD  = 4096;
constexpr int OUTD  = 1024;
constexpr float T_C  = 0.7f;
constexpr float MINC = 1e-5f;
constexpr float MAXC = 10.0f;
constexpr float EPSV = 1e-7f;

__device__ __forceinline__ float bf2f(unsigned int us) {
    return __uint_as_float(us << 16);
}
__device__ __forceinline__ unsigned short f2bf(float f) {
    unsigned int u = __float_as_uint(f);
    u = (u + 0x7FFFu + ((u >> 16) & 1u)) >> 16;   // round-to-nearest-even
    return (unsigned short)u;
}
__device__ __forceinline__ void stage16(const char* src, const unsigned short* dst) {
    __builtin_amdgcn_global_load_lds(
        (const __attribute__((address_space(1))) unsigned int*)src,
        (__attribute__((address_space(3))) unsigned int*)dst, 16, 0, 0);
}

// ------------------------------------------ fused cast f32->bf16 + row dot(x,v)
__global__ __launch_bounds__(256)
void cast_curv(const float* __restrict__ x, const float* __restrict__ v,
               const float* __restrict__ cs,
               unsigned short* __restrict__ xb, float* __restrict__ c)
{
    const int row = blockIdx.x;
    const float* xr = x + (size_t)row * IND;
    unsigned short* ob = xb + (size_t)row * IND;
    float s = 0.f;
    for (int i = threadIdx.x; i < IND / 4; i += 256) {
        float4 w  = ((const float4*)xr)[i];
        float4 vv = ((const float4*)v)[i];
        s += w.x * vv.x + w.y * vv.y + w.z * vv.z + w.w * vv.w;
        ushort4 o;
        o.x = f2bf(w.x); o.y = f2bf(w.y); o.z = f2bf(w.z); o.w = f2bf(w.w);
        ((ushort4*)ob)[i] = o;
    }
    #pragma unroll
    for (int o = 32; o > 0; o >>= 1) s += __shfl_down(s, o, 64);
    __shared__ float red[4];
    if ((threadIdx.x & 63) == 0) red[threadIdx.x >> 6] = s;
    __syncthreads();
    if (threadIdx.x == 0) {
        float tot = red[0] + red[1] + red[2] + red[3];
        float adj = 1.0f / (1.0f + expf(-(tot + cs[0])));
        float cc  = MINC + (MAXC - MINC) * adj;
        c[row] = fminf(fmaxf(cc, MINC), MAXC);
    }
}

// ---------------------- transpose + cast: [K,N]f32 -> [N,K]bf16, 64x64 tiles
__global__ __launch_bounds__(256)
void transpose_cast64(const float* __restrict__ in, unsigned short* __restrict__ out,
                      int K, int N)
{
    __shared__ float tile[64][65];
    const int k0 = blockIdx.y * 64;
    const int n0 = blockIdx.x * 64;
    const int t = threadIdx.x;
    #pragma unroll
    for (int i = 0; i < 4; i++) {
        const int idx = i * 256 + t;
        const int r = idx >> 4, c4 = (idx & 15) * 4;   // 256-B coalesced rows
        float4 v = *(const float4*)(&in[(size_t)(k0 + r) * N + n0 + c4]);
        tile[r][c4 + 0] = v.x; tile[r][c4 + 1] = v.y;
        tile[r][c4 + 2] = v.z; tile[r][c4 + 3] = v.w;
    }
    __syncthreads();
    #pragma unroll
    for (int j = 0; j < 2; j++) {
        const int idx = j * 256 + t;
        const int r = idx >> 3, c8 = (idx & 7) * 8;    // n-row r, k-chunk c8
        us8 o;
        #pragma unroll
        for (int e = 0; e < 8; e++) o[e] = f2bf(tile[c8 + e][r]);
        *(us8*)(&out[(size_t)(n0 + r) * K + k0 + c8]) = o;
    }
}

// ---------------------------------------------------------------- 256^2 GEMM (B^T)
// A [M,K] bf16 rm, Bt [N,K] bf16 rm. BM=BN=256, BK=32, 512 thr = 8 waves (2Mx4N).
// 64 KiB LDS (A[2][256][32] | B[2][256][32]) -> 2 blocks/CU: the tile-boundary
// drain of one block is covered by the co-resident block's MFMA (m114 mechanism;
// the only overlap mechanism with measured success - 7 intra-block schedule
// variants all landed at the LDS+MFMA serialization sum).
// Free-run tile body (R6/R8, best measured): stage burst for kt+1 -> buf^1 at
// tile start; 12 ds_read + 32 MFMA; one vmcnt(0)+s_barrier per tile.
// A-row stripe row = wr*16 + mi*32; swizzle colbyte ^= (row&3)<<4 (64-B rows),
// applied to BOTH stage-src and ds_read (rule 21).
// EPI: 0 = tanh->bf16, 1 = sigmoid->bf16
template<int EPI>
__global__ __launch_bounds__(512, 4)
void gemm256(const unsigned short* __restrict__ A,
             const unsigned short* __restrict__ Bt,
             const float* __restrict__ bias,
             unsigned short* __restrict__ outp,
             int N, int K)
{
    __shared__ unsigned short lds[32768];   // 64 KiB: A [0,32K) | B [32K,64K) bytes

    const int t = threadIdx.x;
    const int w = t >> 6, l = t & 63;
    const int wr = w >> 2, wc = w & 3;      // wave grid 2 x 4
    const int lr = l & 15, lg = l >> 4;

    // bijective XCD swizzle (nwg = 256)
    const int nwg = gridDim.x * gridDim.y;
    const int bid = blockIdx.y * gridDim.x + blockIdx.x;
    const int q8 = nwg >> 3, r8 = nwg & 7;
    const int xcd = bid & 7, off = bid >> 3;
    const int wgid = (xcd < r8 ? xcd * (q8 + 1) : r8 * (q8 + 1) + (xcd - r8) * q8) + off;
    const int by = wgid / gridDim.x;
    const int bx = wgid % gridDim.x;

    const int row0 = by * 256, col0 = bx * 256;
    const unsigned short* Ab = A  + (size_t)row0 * K;
    const unsigned short* Bb = Bt + (size_t)col0 * K;
    const int NT = K >> 5;                  // BK = 32

    f32x4 acc[8][4] = {};

    // ---- staging: 2 loads/thread/matrix; id covers 256 rows x 4 16-B chunks
    const int id0 = t, id1 = 512 + t;
    const int r0 = id0 >> 2;                           // row 0..127
    const int cb = (id0 & 3) * 16;                     // id1&3 == id0&3
    const int s0 = cb ^ ((r0 & 3) << 4);               // (r1&3)==(r0&3) -> same
    const size_t K2 = (size_t)K * 2;
    const char* pA0 = (const char*)Ab + (size_t)r0 * K2 + s0;
    const char* pA1 = pA0 + 128 * K2;                  // rows 128..255
    const char* pB0 = (const char*)Bb + (size_t)r0 * K2 + s0;
    const char* pB1 = pB0 + 128 * K2;
    // LDS dst element offsets within one buf (buf adds +8192 elems = 16 KiB)
    const int dA0 = id0 * 8, dA1 = id1 * 8;
    const int dB0 = 16384 + id0 * 8, dB1 = 16384 + id1 * 8;

    // ---- fragment read bases (byte offsets); row&3 == lr&3 for both A and B
    const int c0 = (lg * 16) ^ ((lr & 3) << 4);
    const int abase = (wr * 16 + lr) * 64 + c0;            // + buf*16384 + mi*2048
    const int bbase = 32768 + (wc * 64 + lr) * 64 + c0;    // + buf*16384 + ni*1024
    const char* ldsb = (const char*)lds;

    // prologue: stage tile 0 -> buf 0, full drain
    stage16(pA0, lds + dA0); stage16(pA1, lds + dA1);
    stage16(pB0, lds + dB0); stage16(pB1, lds + dB1);
    asm volatile("s_waitcnt vmcnt(0)" ::: "memory");
    __builtin_amdgcn_s_barrier();

    for (int kt = 0; kt < NT; ++kt) {
        const int buf = kt & 1, nb = buf ^ 1;
        const bool pre = (kt + 1 < NT);
        pA0 += 64; pA1 += 64; pB0 += 64; pB1 += 64;     // -> tile kt+1 (32 bf16)
        const char* rA = ldsb + buf * 16384 + abase;
        const char* rB = ldsb + buf * 16384 + bbase;
        unsigned short* sb = lds + nb * 8192;

        // stage burst for kt+1 (targets buf^1: no hazard with this tile's reads)
        if (pre) {
            stage16(pA0, sb + dA0); stage16(pA1, sb + dA1);
            stage16(pB0, sb + dB0); stage16(pB1, sb + dB1);
        }

        bf16x8 bfk[4], afk[4];
        #pragma unroll
        for (int ni = 0; ni < 4; ni++) bfk[ni] = *(const bf16x8*)(rB + ni * 1024);
        #pragma unroll
        for (int mi = 0; mi < 4; mi++) afk[mi] = *(const bf16x8*)(rA + mi * 2048);
        __builtin_amdgcn_s_setprio(1);
        #pragma unroll
        for (int mi = 0; mi < 4; mi++)
            #pragma unroll
            for (int ni = 0; ni < 4; ni++)
                acc[mi][ni] = __builtin_amdgcn_mfma_f32_16x16x32_bf16(
                    afk[mi], bfk[ni], acc[mi][ni], 0, 0, 0);
        __builtin_amdgcn_s_setprio(0);

        #pragma unroll
        for (int mi = 0; mi < 4; mi++) afk[mi] = *(const bf16x8*)(rA + 8192 + mi * 2048);
        __builtin_amdgcn_s_setprio(1);
        #pragma unroll
        for (int mi = 0; mi < 4; mi++)
            #pragma unroll
            for (int ni = 0; ni < 4; ni++)
                acc[4 + mi][ni] = __builtin_amdgcn_mfma_f32_16x16x32_bf16(
                    afk[mi], bfk[ni], acc[4 + mi][ni], 0, 0, 0);
        __builtin_amdgcn_s_setprio(0);

        // tile boundary: kt+1 staged (issued a full tile ago), all reads done
        asm volatile("s_waitcnt vmcnt(0)" ::: "memory");
        __builtin_amdgcn_s_barrier();
    }

    // epilogue: m-frag mi at row wr*16 + mi*32; within frag row = lg*4+r, col = lr
    const int colb = col0 + wc * 64;
    #pragma unroll
    for (int ni = 0; ni < 4; ni++) {
        const int cg = colb + ni * 16 + lr;
        const float bv = bias[cg];
        #pragma unroll
        for (int mi = 0; mi < 8; mi++) {
            #pragma unroll
            for (int r = 0; r < 4; r++) {
                const int rg = row0 + wr * 16 + mi * 32 + lg * 4 + r;
                float v = acc[mi][ni][r] + bv;
                if constexpr (EPI == 0) v = tanhf(v);
                else                    v = 1.0f / (1.0f + expf(-v));
                outp[(size_t)rg * N + cg] = f2bf(v);
            }
        }
    }
}

// ------------------------------------------- 128^2 pipelined GEMM (B^T), f32 out
// BM=BN=128, BK=64, 512 thr = 8 waves (2Mx4N), per-wave 64x32. Free-run body,
// one vmcnt(0)+barrier per tile. Swizzle colbyte ^= (row&3)<<4 (both sides).
// 64 KiB LDS -> 2 blocks/CU possible.
__global__ __launch_bounds__(512, 2)
void gemm_out128(const unsigned short* __restrict__ A,
                 const unsigned short* __restrict__ Bt,
                 const float* __restrict__ bias,
                 float* __restrict__ outp,
                 int N, int K)
{
    __shared__ unsigned short lds[32768];   // 64 KiB

    const int t = threadIdx.x;
    const int w = t >> 6, l = t & 63;
    const int wr = w >> 2, wc = w & 3;      // wave grid 2 x 4
    const int lr = l & 15, lg = l >> 4;

    const int nwg = gridDim.x * gridDim.y;
    const int bid = blockIdx.y * gridDim.x + blockIdx.x;
    const int q8 = nwg >> 3, r8 = nwg & 7;
    const int xcd = bid & 7, off = bid >> 3;
    const int wgid = (xcd < r8 ? xcd * (q8 + 1) : r8 * (q8 + 1) + (xcd - r8) * q8) + off;
    const int by = wgid / gridDim.x;
    const int bx = wgid % gridDim.x;

    const int row0 = by * 128, col0 = bx * 128;
    const unsigned short* Ab = A  + (size_t)row0 * K;
    const unsigned short* Bb = Bt + (size_t)col0 * K;
    const int NT = K >> 6;

    f32x4 acc[4][2] = {};

    const int sr = t >> 2;
    const int scb = ((t & 3) * 16) ^ ((sr & 3) << 4);
    const size_t K2 = (size_t)K * 2;
    const char* pAk0 = (const char*)Ab + (size_t)sr * K2 + scb;
    const char* pAk1 = pAk0 + 64;
    const char* pBk0 = (const char*)Bb + (size_t)sr * K2 + scb;
    const char* pBk1 = pBk0 + 64;
    const int dAk0 = t * 8,          dAk1 = 4096 + t * 8;
    const int dBk0 = 16384 + t * 8,  dBk1 = 20480 + t * 8;

    const int csw = (lg * 16) ^ ((lr & 3) << 4);
    const int aof = (wr * 64 + lr) * 64 + csw;
    const int bof = 32768 + (wc * 32 + lr) * 64 + csw;
    const char* ldsb = (const char*)lds;

    stage16(pAk0, lds + dAk0); stage16(pBk0, lds + dBk0);
    stage16(pAk1, lds + dAk1); stage16(pBk1, lds + dBk1);
    asm volatile("s_waitcnt vmcnt(0)" ::: "memory");
    __builtin_amdgcn_s_barrier();

    for (int kt = 0; kt < NT; ++kt) {
        const int buf = kt & 1, nb = buf ^ 1;
        const bool pre = (kt + 1 < NT);
        pAk0 += 128; pAk1 += 128; pBk0 += 128; pBk1 += 128;
        const int bufby = buf * 16384;
        const int bsh   = nb * 8192;
        const char* rA0 = ldsb + bufby + aof;
        const char* rB0 = ldsb + bufby + bof;
        const char* rA1 = rA0 + 8192;
        const char* rB1 = rB0 + 8192;

        if (pre) {
            stage16(pAk0, lds + bsh + dAk0); stage16(pBk0, lds + bsh + dBk0);
            stage16(pAk1, lds + bsh + dAk1); stage16(pBk1, lds + bsh + dBk1);
        }

        bf16x8 af[4], bfr[2];

        // kk0
        #pragma unroll
        for (int nj = 0; nj < 2; nj++) bfr[nj] = *(const bf16x8*)(rB0 + nj * 1024);
        #pragma unroll
        for (int mi = 0; mi < 4; mi++) af[mi] = *(const bf16x8*)(rA0 + mi * 1024);
        __builtin_amdgcn_s_setprio(1);
        #pragma unroll
        for (int mi = 0; mi < 4; mi++)
            #pragma unroll
            for (int nj = 0; nj < 2; nj++)
                acc[mi][nj] = __builtin_amdgcn_mfma_f32_16x16x32_bf16(
                    af[mi], bfr[nj], acc[mi][nj], 0, 0, 0);
        __builtin_amdgcn_s_setprio(0);

        // kk1
        #pragma unroll
        for (int nj = 0; nj < 2; nj++) bfr[nj] = *(const bf16x8*)(rB1 + nj * 1024);
        #pragma unroll
        for (int mi = 0; mi < 4; mi++) af[mi] = *(const bf16x8*)(rA1 + mi * 1024);
        __builtin_amdgcn_s_setprio(1);
        #pragma unroll
        for (int mi = 0; mi < 4; mi++)
            #pragma unroll
            for (int nj = 0; nj < 2; nj++)
                acc[mi][nj] = __builtin_amdgcn_mfma_f32_16x16x32_bf16(
                    af[mi], bfr[nj], acc[mi][nj], 0, 0, 0);
        __builtin_amdgcn_s_setprio(0);

        asm volatile("s_waitcnt vmcnt(0)" ::: "memory");
        __builtin_amdgcn_s_barrier();
    }

    #pragma unroll
    for (int nj = 0; nj < 2; nj++) {
        const int cg = col0 + wc * 32 + nj * 16 + lr;
        const float bv = bias[cg];
        #pragma unroll
        for (int mi = 0; mi < 4; mi++)
            #pragma unroll
            for (int r = 0; r < 4; r++) {
                const int rg = row0 + wr * 64 + mi * 16 + lg * 4 + r;
                outp[(size_t)rg * N + cg] = acc[mi][nj][r] + bv;
            }
    }
}

// ---------------------------------------------------------------- v = proj @ curv_feat
__global__ __launch_bounds__(256)
void proj_cf(const float* __restrict__ proj, const float* __restrict__ cf,
             float* __restrict__ v)
{
    int i = blockIdx.x * 256 + threadIdx.x;
    if (i < IND) {
        float s = 0.f;
        #pragma unroll
        for (int j = 0; j < 16; j++) s += proj[i * 16 + j] * cf[j];
        v[i] = s;
    }
}

// ---------------------------------------------------------------- Poincare layer
__global__ __launch_bounds__(256)
void poincare_kernel(const unsigned short* __restrict__ hb,
                     const unsigned short* __restrict__ ub,
                     const float* __restrict__ c,
                     unsigned short* __restrict__ zb)
{
    const int row = blockIdx.x;
    const int t = threadIdx.x;
    const size_t base = (size_t)row * HIDD;

    float hv[16], uv[16];
    float h2 = 0.f, u2 = 0.f, hu = 0.f;
    #pragma unroll
    for (int q = 0; q < 2; q++) {
        const int e0 = (q * 256 + t) * 8;
        uint4 hc = *(const uint4*)(hb + base + e0);
        uint4 uc = *(const uint4*)(ub + base + e0);
        const unsigned int hw[4] = {hc.x, hc.y, hc.z, hc.w};
        const unsigned int uw[4] = {uc.x, uc.y, uc.z, uc.w};
        #pragma unroll
        for (int i = 0; i < 4; i++) {
            float h0 = bf2f(hw[i] & 0xFFFFu), h1 = bf2f(hw[i] >> 16);
            float u0 = bf2f(uw[i] & 0xFFFFu), u1 = bf2f(uw[i] >> 16);
            hv[q * 8 + 2 * i]     = h0; hv[q * 8 + 2 * i + 1] = h1;
            uv[q * 8 + 2 * i]     = u0; uv[q * 8 + 2 * i + 1] = u1;
            h2 += h0 * h0 + h1 * h1;
            u2 += u0 * u0 + u1 * u1;
            hu += h0 * u0 + h1 * u1;
        }
    }
    #pragma unroll
    for (int o = 32; o > 0; o >>= 1) {
        h2 += __shfl_down(h2, o, 64);
        u2 += __shfl_down(u2, o, 64);
        hu += __shfl_down(hu, o, 64);
    }
    __shared__ float red[3][4];
    const int w = t >> 6;
    if ((t & 63) == 0) { red[0][w] = h2; red[1][w] = u2; red[2][w] = hu; }
    __syncthreads();
    h2 = red[0][0] + red[0][1] + red[0][2] + red[0][3];
    u2 = red[1][0] + red[1][1] + red[1][2] + red[1][3];
    hu = red[2][0] + red[2][1] + red[2][2] + red[2][3];

    const float cc = c[row];
    const float sc = sqrtf(cc);
    float nh = fmaxf(sqrtf(h2), EPSV);
    float nu = fmaxf(sqrtf(u2), EPSV);
    float ah = fminf(fmaxf(sc * nh, EPSV), 1.0f - 1e-5f);
    float au = fminf(fmaxf(sc * nu, EPSV), 1.0f - 1e-5f);
    float ath = 0.5f * log1pf(2.0f * ah / (1.0f - ah));
    float atu = 0.5f * log1pf(2.0f * au / (1.0f - au));
    float alpha = tanhf((1.0f - T_C) * ath) / (sc * nh);
    float beta  = tanhf(T_C * atu) / (sc * nu);
    float x2 = alpha * alpha * h2;
    float y2 = beta * beta * u2;
    float xy = alpha * beta * hu;
    float den = 1.0f + 2.0f * cc * xy + cc * cc * x2 * y2;
    den = fmaxf(den, EPSV);
    float ca = (1.0f + 2.0f * cc * xy + cc * y2) * alpha / den;
    float cb = (1.0f - cc * x2) * beta / den;
    if (isnan(ca) || isnan(cb)) { ca = 1.0f; cb = 0.0f; }

    #pragma unroll
    for (int q = 0; q < 2; q++) {
        const int e0 = (q * 256 + t) * 8;
        unsigned int ow[4];
        #pragma unroll
        for (int i = 0; i < 4; i++) {
            float z0 = ca * hv[q * 8 + 2 * i]     + cb * uv[q * 8 + 2 * i];
            float z1 = ca * hv[q * 8 + 2 * i + 1] + cb * uv[q * 8 + 2 * i + 1];
            ow[i] = (unsigned int)f2bf(z0) | ((unsigned int)f2bf(z1) << 16);
        }
        *(uint4*)(zb + base + e0) = make_uint4(ow[0], ow[1], ow[2], ow[3]);
    }
}

// ---------------------------------------------------------------------------
extern "C" void kernel_launch(void* const* d_in, const int* in_sizes, int n_in,
                              void* d_out, int out_size, void* d_ws, size_t ws_size,
                              hipStream_t stream)
{
    const float* x    = (const float*)d_in[0];
    const float* W1   = (const float*)d_in[1];
    const float* b1   = (const float*)d_in[2];
    const float* W2   = (const float*)d_in[3];
    const float* b2   = (const float*)d_in[4];
    const float* Wout = (const float*)d_in[5];
    const float* bout = (const float*)d_in[6];
    const float* cf   = (const float*)d_in[7];
    const float* cs   = (const float*)d_in[8];
    const float* proj = (const float*)d_in[9];
    float* out = (float*)d_out;

    char* ws = (char*)d_ws;
    unsigned short* x_bf = (unsigned short*)(ws);               // 32 MiB (reused as z_bf)
    unsigned short* w_bf = (unsigned short*)(ws + (33554432));  // 32 MiB (W1T/W2T/WoutT)
    unsigned short* h_bf = (unsigned short*)(ws + (67108864));  // 32 MiB
    unsigned short* u_bf = (unsigned short*)(ws + (100663296)); // 32 MiB
    float* vvec = (float*)(ws + 134217728);                     // 16 KiB
    float* cvec = (float*)(ws + 134217728 + 16384);             // 16 KiB

    // 1. curvature prep + fused cast/row-dot
    proj_cf<<<IND / 256, 256, 0, stream>>>(proj, cf, vvec);
    cast_curv<<<BATCH, 256, 0, stream>>>(x, vvec, cs, x_bf, cvec);

    // 2. h = tanh(x @ W1 + b1)
    transpose_cast64<<<dim3(HIDD / 64, IND / 64), 256, 0, stream>>>(W1, w_bf, IND, HIDD);
    gemm256<0><<<dim3(HIDD / 256, BATCH / 256), 512, 0, stream>>>(x_bf, w_bf, b1, h_bf, HIDD, IND);

    // 3. u = sigmoid(h @ W2 + b2)
    transpose_cast64<<<dim3(HIDD / 64, HIDD / 64), 256, 0, stream>>>(W2, w_bf, HIDD, HIDD);
    gemm256<1><<<dim3(HIDD / 256, BATCH / 256), 512, 0, stream>>>(h_bf, w_bf, b2, u_bf, HIDD, HIDD);

    // 4. z = poincare(h, u, c)   (z overwrites x_bf)
    poincare_kernel<<<BATCH, 256, 0, stream>>>(h_bf, u_bf, cvec, x_bf);

    // 5. out = z @ Wout + bout
    transpose_cast64<<<dim3(OUTD / 64, HIDD / 64), 256, 0, stream>>>(Wout, w_bf, HIDD, OUTD);
    gemm_out128<<<dim3(OUTD / 128, BATCH / 128), 512, 0, stream>>>(x_bf, w_bf, bout, out, OUTD, HIDD);
}

// Round 12
// 385.786 us; speedup vs baseline: 5.8310x; 5.8310x over previous
//
#include <hip/hip_runtime.h>
#include <hip/hip_bf16.h>
#include <math.h>

// ---------------------------------------------------------------------------
// ImprovedDynamicCurvatureMLP on MI355X (gfx950)  -- R6-best revert + out-GEMM occupancy
//   x_bf,c = fused cast + per-row curvature
//   h_bf  = gemm256<tanh>(x_bf, W1^T)   [256^2, 8-wave, kk-split, hoisted addr]
//   u_bf  = gemm256<sigmoid>(h_bf, W2^T)
//   z_bf  = a(row)*h + b(row)*u         (Poincare layer = row scalars)
//   out   = gemm_out128(z_bf, Wout^T)   [128^2 pipelined, 2 blocks/CU]
// ---------------------------------------------------------------------------

typedef __attribute__((ext_vector_type(8)))  __bf16 bf16x8;
typedef __attribute__((ext_vector_type(4)))  float  f32x4;
typedef __attribute__((ext_vector_type(8)))  unsigned short us8;

constexpr int BATCH = 4096;
constexpr int IND   = 4096;
constexpr int HIDD  = 4096;
constexpr int OUTD  = 1024;
constexpr float T_C  = 0.7f;
constexpr float MINC = 1e-5f;
constexpr float MAXC = 10.0f;
constexpr float EPSV = 1e-7f;

__device__ __forceinline__ float bf2f(unsigned int us) {
    return __uint_as_float(us << 16);
}
__device__ __forceinline__ unsigned short f2bf(float f) {
    unsigned int u = __float_as_uint(f);
    u = (u + 0x7FFFu + ((u >> 16) & 1u)) >> 16;   // round-to-nearest-even
    return (unsigned short)u;
}
__device__ __forceinline__ void stage16(const void* src, const void* dst) {
    __builtin_amdgcn_global_load_lds(
        (const __attribute__((address_space(1))) unsigned int*)src,
        (__attribute__((address_space(3))) unsigned int*)dst, 16, 0, 0);
}

// ------------------------------------------ fused cast f32->bf16 + row dot(x,v)
__global__ __launch_bounds__(256)
void cast_curv(const float* __restrict__ x, const float* __restrict__ v,
               const float* __restrict__ cs,
               unsigned short* __restrict__ xb, float* __restrict__ c)
{
    const int row = blockIdx.x;
    const float* xr = x + (size_t)row * IND;
    unsigned short* ob = xb + (size_t)row * IND;
    float s = 0.f;
    for (int i = threadIdx.x; i < IND / 4; i += 256) {
        float4 w  = ((const float4*)xr)[i];
        float4 vv = ((const float4*)v)[i];
        s += w.x * vv.x + w.y * vv.y + w.z * vv.z + w.w * vv.w;
        ushort4 o;
        o.x = f2bf(w.x); o.y = f2bf(w.y); o.z = f2bf(w.z); o.w = f2bf(w.w);
        ((ushort4*)ob)[i] = o;
    }
    #pragma unroll
    for (int o = 32; o > 0; o >>= 1) s += __shfl_down(s, o, 64);
    __shared__ float red[4];
    if ((threadIdx.x & 63) == 0) red[threadIdx.x >> 6] = s;
    __syncthreads();
    if (threadIdx.x == 0) {
        float tot = red[0] + red[1] + red[2] + red[3];
        float adj = 1.0f / (1.0f + expf(-(tot + cs[0])));
        float cc  = MINC + (MAXC - MINC) * adj;
        c[row] = fminf(fmaxf(cc, MINC), MAXC);
    }
}

// ---------------------- transpose + cast: [K,N]f32 -> [N,K]bf16, 64x64 tiles
__global__ __launch_bounds__(256)
void transpose_cast64(const float* __restrict__ in, unsigned short* __restrict__ out,
                      int K, int N)
{
    __shared__ float tile[64][65];
    const int k0 = blockIdx.y * 64;
    const int n0 = blockIdx.x * 64;
    const int t = threadIdx.x;
    #pragma unroll
    for (int i = 0; i < 4; i++) {
        const int idx = i * 256 + t;
        const int r = idx >> 4, c4 = (idx & 15) * 4;   // 256-B coalesced rows
        float4 v = *(const float4*)(&in[(size_t)(k0 + r) * N + n0 + c4]);
        tile[r][c4 + 0] = v.x; tile[r][c4 + 1] = v.y;
        tile[r][c4 + 2] = v.z; tile[r][c4 + 3] = v.w;
    }
    __syncthreads();
    #pragma unroll
    for (int j = 0; j < 2; j++) {
        const int idx = j * 256 + t;
        const int r = idx >> 3, c8 = (idx & 7) * 8;    // n-row r, k-chunk c8
        us8 o;
        #pragma unroll
        for (int e = 0; e < 8; e++) o[e] = f2bf(tile[c8 + e][r]);
        *(us8*)(&out[(size_t)(n0 + r) * K + k0 + c8]) = o;
    }
}

// ---------------------------------------------------------------- 256^2 GEMM (B^T)
// A [M,K] bf16 rm, Bt [N,K] bf16 rm. BM=BN=256, BK=64, 512 thr = 8 waves (2Mx4N).
// R6-best: kk-split 4-phase with HOISTED addresses.
//   p0: (mi0-3,kk0) reads 4B+4A; stage Ah0,Bh0(t+1); 16 MFMA; vmcnt(4); bar
//   p1: (mi4-7,kk0) reads 4A;    stage Bh1,Ah1(t+1); 16 MFMA;            bar
//   p2: (mi0-3,kk1) reads 4B+4A;                     16 MFMA;            bar
//   p3: (mi4-7,kk1) reads 4A;                        16 MFMA; vmcnt(2);  bar
// Ledger: p0-end outst = Ah1(t)2+Ah0,Bh0(t+1)4 = 6, vmcnt(4) retires Ah1(t);
// p3-end outst = 8, vmcnt(2) retires Ah0/Bh0/Bh1(t+1), Ah1(t+1) in flight.
// A-row stripe row = wr*16 + mi*32; swizzle colbyte ^= ((row&7)<<4) both sides.
// EPI: 0 = tanh->bf16, 1 = sigmoid->bf16
template<int EPI>
__global__ __launch_bounds__(512, 2)
void gemm256(const unsigned short* __restrict__ A,
             const unsigned short* __restrict__ Bt,
             const float* __restrict__ bias,
             unsigned short* __restrict__ outp,
             int N, int K)
{
    __shared__ unsigned short lds[4 * 256 * 64];    // A[2][256][64] | B[2][256][64]

    const int t = threadIdx.x;
    const int w = t >> 6, l = t & 63;
    const int wr = w >> 2, wc = w & 3;      // wave grid 2 x 4
    const int lr = l & 15, lg = l >> 4;

    // bijective XCD swizzle (nwg = 256)
    const int nwg = gridDim.x * gridDim.y;
    const int bid = blockIdx.y * gridDim.x + blockIdx.x;
    const int q8 = nwg >> 3, r8 = nwg & 7;
    const int xcd = bid & 7, off = bid >> 3;
    const int wgid = (xcd < r8 ? xcd * (q8 + 1) : r8 * (q8 + 1) + (xcd - r8) * q8) + off;
    const int by = wgid / gridDim.x;
    const int bx = wgid % gridDim.x;

    const int row0 = by * 256, col0 = bx * 256;
    const unsigned short* Ab = A  + (size_t)row0 * K;
    const unsigned short* Bb = Bt + (size_t)col0 * K;
    const int NT = K >> 6;

    f32x4 acc[8][4] = {};

    // ---- hoisted staging addresses: src = base + row*K*2 + (cb ^ ((row&7)<<4))
    const int id0 = t, id1 = 512 + t;
    const int r0 = id0 >> 3, r1 = id1 >> 3;            // rows within a 128-half
    const int cb0 = (id0 & 7) * 16, cb1 = (id1 & 7) * 16;
    const int s0 = cb0 ^ ((r0 & 7) << 4), s1 = cb1 ^ ((r1 & 7) << 4);
    const size_t K2 = (size_t)K * 2;
    const char* pA00 = (const char*)Ab + (size_t)r0 * K2 + s0;          // Ah0
    const char* pA01 = (const char*)Ab + (size_t)r1 * K2 + s1;
    const char* pA10 = pA00 + 128 * K2;                                  // Ah1
    const char* pA11 = pA01 + 128 * K2;
    const char* pB00 = (const char*)Bb + (size_t)r0 * K2 + s0;          // Bh0
    const char* pB01 = (const char*)Bb + (size_t)r1 * K2 + s1;
    const char* pB10 = pB00 + 128 * K2;                                  // Bh1
    const char* pB11 = pB01 + 128 * K2;
    // LDS dst element offsets (linear, rule 21): A region [0,32768), B +32768
    const int dA0a = id0 * 8,          dA0b = id1 * 8;
    const int dA1a = 8192 + id0 * 8,   dA1b = 8192 + id1 * 8;
    const int dB0a = 32768 + id0 * 8,  dB0b = 32768 + id1 * 8;
    const int dB1a = 40960 + id0 * 8,  dB1b = 40960 + id1 * 8;

    // ---- hoisted read bases (byte offsets into lds)
    const int sw = (lr & 7) << 4;
    const int c0 = (lg * 16) ^ sw;
    const int c1 = (64 + lg * 16) ^ sw;
    const int aofc0 = (wr * 16 + lr) * 128 + c0;
    const int aofc1 = (wr * 16 + lr) * 128 + c1;
    const int bofc0 = 65536 + (wc * 64 + lr) * 128 + c0;
    const int bofc1 = 65536 + (wc * 64 + lr) * 128 + c1;
    const char* ldsb = (const char*)lds;

    // prologue: tile 0 -> buf 0: Ah0, Bh0, Bh1, Ah1; keep Ah1 (2 loads) in flight
    stage16(pA00, lds + dA0a); stage16(pA01, lds + dA0b);
    stage16(pB00, lds + dB0a); stage16(pB01, lds + dB0b);
    stage16(pB10, lds + dB1a); stage16(pB11, lds + dB1b);
    stage16(pA10, lds + dA1a); stage16(pA11, lds + dA1b);
    asm volatile("s_waitcnt vmcnt(2)" ::: "memory");
    __builtin_amdgcn_s_barrier();

    for (int kt = 0; kt < NT; ++kt) {
        const int buf = kt & 1, nb = buf ^ 1;
        const bool pre = (kt + 1 < NT);
        // advance staging pointers to tile kt+1
        pA00 += 128; pA01 += 128; pA10 += 128; pA11 += 128;
        pB00 += 128; pB01 += 128; pB10 += 128; pB11 += 128;
        const int bufby = buf * 32768;          // read-side byte offset
        const int bsh   = nb * 16384;           // stage-side element offset
        const char* rA0 = ldsb + bufby + aofc0;
        const char* rA1 = ldsb + bufby + aofc1;
        const char* rB0 = ldsb + bufby + bofc0;
        const char* rB1 = ldsb + bufby + bofc1;

        bf16x8 bfk[4], afk[4];

        // -------- p0: (mi0-3, kk0); stage Ah0,Bh0(t+1)
        #pragma unroll
        for (int ni = 0; ni < 4; ni++) bfk[ni] = *(const bf16x8*)(rB0 + ni * 2048);
        #pragma unroll
        for (int mi = 0; mi < 4; mi++) afk[mi] = *(const bf16x8*)(rA0 + mi * 4096);
        if (pre) {
            stage16(pA00, lds + bsh + dA0a); stage16(pA01, lds + bsh + dA0b);
            stage16(pB00, lds + bsh + dB0a); stage16(pB01, lds + bsh + dB0b);
        }
        __builtin_amdgcn_s_setprio(1);
        #pragma unroll
        for (int mi = 0; mi < 4; mi++)
            #pragma unroll
            for (int ni = 0; ni < 4; ni++)
                acc[mi][ni] = __builtin_amdgcn_mfma_f32_16x16x32_bf16(
                    afk[mi], bfk[ni], acc[mi][ni], 0, 0, 0);
        __builtin_amdgcn_s_setprio(0);
        if (pre) asm volatile("s_waitcnt vmcnt(4)" ::: "memory");
        else     asm volatile("s_waitcnt vmcnt(0)" ::: "memory");
        __builtin_amdgcn_s_barrier();

        // -------- p1: (mi4-7, kk0); stage Bh1,Ah1(t+1)
        #pragma unroll
        for (int mi = 0; mi < 4; mi++) afk[mi] = *(const bf16x8*)(rA0 + 16384 + mi * 4096);
        if (pre) {
            stage16(pB10, lds + bsh + dB1a); stage16(pB11, lds + bsh + dB1b);
            stage16(pA10, lds + bsh + dA1a); stage16(pA11, lds + bsh + dA1b);
        }
        __builtin_amdgcn_s_setprio(1);
        #pragma unroll
        for (int mi = 0; mi < 4; mi++)
            #pragma unroll
            for (int ni = 0; ni < 4; ni++)
                acc[4 + mi][ni] = __builtin_amdgcn_mfma_f32_16x16x32_bf16(
                    afk[mi], bfk[ni], acc[4 + mi][ni], 0, 0, 0);
        __builtin_amdgcn_s_setprio(0);
        __builtin_amdgcn_s_barrier();

        // -------- p2: (mi0-3, kk1)
        #pragma unroll
        for (int ni = 0; ni < 4; ni++) bfk[ni] = *(const bf16x8*)(rB1 + ni * 2048);
        #pragma unroll
        for (int mi = 0; mi < 4; mi++) afk[mi] = *(const bf16x8*)(rA1 + mi * 4096);
        __builtin_amdgcn_s_setprio(1);
        #pragma unroll
        for (int mi = 0; mi < 4; mi++)
            #pragma unroll
            for (int ni = 0; ni < 4; ni++)
                acc[mi][ni] = __builtin_amdgcn_mfma_f32_16x16x32_bf16(
                    afk[mi], bfk[ni], acc[mi][ni], 0, 0, 0);
        __builtin_amdgcn_s_setprio(0);
        __builtin_amdgcn_s_barrier();

        // -------- p3: (mi4-7, kk1)
        #pragma unroll
        for (int mi = 0; mi < 4; mi++) afk[mi] = *(const bf16x8*)(rA1 + 16384 + mi * 4096);
        __builtin_amdgcn_s_setprio(1);
        #pragma unroll
        for (int mi = 0; mi < 4; mi++)
            #pragma unroll
            for (int ni = 0; ni < 4; ni++)
                acc[4 + mi][ni] = __builtin_amdgcn_mfma_f32_16x16x32_bf16(
                    afk[mi], bfk[ni], acc[4 + mi][ni], 0, 0, 0);
        __builtin_amdgcn_s_setprio(0);
        if (pre) asm volatile("s_waitcnt vmcnt(2)" ::: "memory");
        else     asm volatile("s_waitcnt vmcnt(0)" ::: "memory");
        __builtin_amdgcn_s_barrier();
    }

    // epilogue: m-frag mi at row wr*16 + mi*32; within frag row = lg*4+r, col = lr
    const int colb = col0 + wc * 64;
    #pragma unroll
    for (int ni = 0; ni < 4; ni++) {
        const int cg = colb + ni * 16 + lr;
        const float bv = bias[cg];
        #pragma unroll
        for (int mi = 0; mi < 8; mi++) {
            #pragma unroll
            for (int r = 0; r < 4; r++) {
                const int rg = row0 + wr * 16 + mi * 32 + lg * 4 + r;
                float v = acc[mi][ni][r] + bv;
                if constexpr (EPI == 0) v = tanhf(v);
                else                    v = 1.0f / (1.0f + expf(-v));
                outp[(size_t)rg * N + cg] = f2bf(v);
            }
        }
    }
}

// ------------------------------------------- 128^2 pipelined GEMM (B^T), f32 out
// BM=BN=128, BK=64, 512 thr = 8 waves (2Mx4N), per-wave 64x32.
// LDS 64 KiB + launch_bounds(512,4) -> 2 blocks/CU (cross-block overlap covers
// per-phase drains). 2-phase counted vmcnt(2): p0-end retires kk1(t), p1-end
// retires kk0(t+1); never drains to 0 mid-loop.
// Swizzle colbyte ^= ((row&3)<<4) on both sides (64-B kk-half rows).
__global__ __launch_bounds__(512, 4)
void gemm_out128(const unsigned short* __restrict__ A,
                 const unsigned short* __restrict__ Bt,
                 const float* __restrict__ bias,
                 float* __restrict__ outp,
                 int N, int K)
{
    __shared__ unsigned short lds[32768];   // 64 KiB

    const int t = threadIdx.x;
    const int w = t >> 6, l = t & 63;
    const int wr = w >> 2, wc = w & 3;      // wave grid 2 x 4
    const int lr = l & 15, lg = l >> 4;

    const int nwg = gridDim.x * gridDim.y;
    const int bid = blockIdx.y * gridDim.x + blockIdx.x;
    const int q8 = nwg >> 3, r8 = nwg & 7;
    const int xcd = bid & 7, off = bid >> 3;
    const int wgid = (xcd < r8 ? xcd * (q8 + 1) : r8 * (q8 + 1) + (xcd - r8) * q8) + off;
    const int by = wgid / gridDim.x;
    const int bx = wgid % gridDim.x;

    const int row0 = by * 128, col0 = bx * 128;
    const unsigned short* Ab = A  + (size_t)row0 * K;
    const unsigned short* Bb = Bt + (size_t)col0 * K;
    const int NT = K >> 6;

    f32x4 acc[4][2] = {};

    // staging: thread t covers row = t>>2, 16-B chunk (t&3) of a 128x64-B sub-tile
    const int sr = t >> 2;
    const int scb = ((t & 3) * 16) ^ ((sr & 3) << 4);
    const size_t K2 = (size_t)K * 2;
    const char* pAk0 = (const char*)Ab + (size_t)sr * K2 + scb;
    const char* pAk1 = pAk0 + 64;
    const char* pBk0 = (const char*)Bb + (size_t)sr * K2 + scb;
    const char* pBk1 = pBk0 + 64;
    // LDS dst BYTE offsets: A [0,16384)/buf: kkh*8192 + t*16; buf +16384; B +32768
    const int dAk0 = t * 16,          dAk1 = 8192 + t * 16;
    const int dBk0 = 32768 + t * 16,  dBk1 = 40960 + t * 16;

    // read bases (byte offsets): row stride 64 B, kkh stride 8192 B, buf 16384 B
    const int csw = (lg * 16) ^ ((lr & 3) << 4);
    const int aof = (wr * 64 + lr) * 64 + csw;
    const int bof = 32768 + (wc * 32 + lr) * 64 + csw;
    char* ldsc = (char*)lds;

    // prologue: Akk0, Bkk0, Akk1, Bkk1 of tile 0 -> buf 0; retire kk0 pair
    stage16(pAk0, ldsc + dAk0); stage16(pBk0, ldsc + dBk0);
    stage16(pAk1, ldsc + dAk1); stage16(pBk1, ldsc + dBk1);
    asm volatile("s_waitcnt vmcnt(2)" ::: "memory");
    __builtin_amdgcn_s_barrier();

    for (int kt = 0; kt < NT; ++kt) {
        const int buf = kt & 1, nb = buf ^ 1;
        const bool pre = (kt + 1 < NT);
        pAk0 += 128; pAk1 += 128; pBk0 += 128; pBk1 += 128;
        const int bufby = buf * 16384;
        const int bsh   = nb * 16384;
        const char* rA0 = (const char*)lds + bufby + aof;
        const char* rB0 = (const char*)lds + bufby + bof;
        const char* rA1 = rA0 + 8192;
        const char* rB1 = rB0 + 8192;

        bf16x8 af[4], bfr[2];

        // -------- p0: kk0; stage Akk0,Bkk0(t+1)
        #pragma unroll
        for (int nj = 0; nj < 2; nj++) bfr[nj] = *(const bf16x8*)(rB0 + nj * 1024);
        #pragma unroll
        for (int mi = 0; mi < 4; mi++) af[mi] = *(const bf16x8*)(rA0 + mi * 1024);
        if (pre) { stage16(pAk0, ldsc + bsh + dAk0); stage16(pBk0, ldsc + bsh + dBk0); }
        __builtin_amdgcn_s_setprio(1);
        #pragma unroll
        for (int mi = 0; mi < 4; mi++)
            #pragma unroll
            for (int nj = 0; nj < 2; nj++)
                acc[mi][nj] = __builtin_amdgcn_mfma_f32_16x16x32_bf16(
                    af[mi], bfr[nj], acc[mi][nj], 0, 0, 0);
        __builtin_amdgcn_s_setprio(0);
        if (pre) asm volatile("s_waitcnt vmcnt(2)" ::: "memory");
        else     asm volatile("s_waitcnt vmcnt(0)" ::: "memory");
        __builtin_amdgcn_s_barrier();

        // -------- p1: kk1; stage Akk1,Bkk1(t+1)
        #pragma unroll
        for (int nj = 0; nj < 2; nj++) bfr[nj] = *(const bf16x8*)(rB1 + nj * 1024);
        #pragma unroll
        for (int mi = 0; mi < 4; mi++) af[mi] = *(const bf16x8*)(rA1 + mi * 1024);
        if (pre) { stage16(pAk1, ldsc + bsh + dAk1); stage16(pBk1, ldsc + bsh + dBk1); }
        __builtin_amdgcn_s_setprio(1);
        #pragma unroll
        for (int mi = 0; mi < 4; mi++)
            #pragma unroll
            for (int nj = 0; nj < 2; nj++)
                acc[mi][nj] = __builtin_amdgcn_mfma_f32_16x16x32_bf16(
                    af[mi], bfr[nj], acc[mi][nj], 0, 0, 0);
        __builtin_amdgcn_s_setprio(0);
        if (pre) asm volatile("s_waitcnt vmcnt(2)" ::: "memory");
        else     asm volatile("s_waitcnt vmcnt(0)" ::: "memory");
        __builtin_amdgcn_s_barrier();
    }

    // epilogue
    #pragma unroll
    for (int nj = 0; nj < 2; nj++) {
        const int cg = col0 + wc * 32 + nj * 16 + lr;
        const float bv = bias[cg];
        #pragma unroll
        for (int mi = 0; mi < 4; mi++)
            #pragma unroll
            for (int r = 0; r < 4; r++) {
                const int rg = row0 + wr * 64 + mi * 16 + lg * 4 + r;
                outp[(size_t)rg * N + cg] = acc[mi][nj][r] + bv;
            }
    }
}

// ---------------------------------------------------------------- v = proj @ curv_feat
__global__ __launch_bounds__(256)
void proj_cf(const float* __restrict__ proj, const float* __restrict__ cf,
             float* __restrict__ v)
{
    int i = blockIdx.x * 256 + threadIdx.x;
    if (i < IND) {
        float s = 0.f;
        #pragma unroll
        for (int j = 0; j < 16; j++) s += proj[i * 16 + j] * cf[j];
        v[i] = s;
    }
}

// ---------------------------------------------------------------- Poincare layer
__global__ __launch_bounds__(256)
void poincare_kernel(const unsigned short* __restrict__ hb,
                     const unsigned short* __restrict__ ub,
                     const float* __restrict__ c,
                     unsigned short* __restrict__ zb)
{
    const int row = blockIdx.x;
    const int t = threadIdx.x;
    const size_t base = (size_t)row * HIDD;

    float hv[16], uv[16];
    float h2 = 0.f, u2 = 0.f, hu = 0.f;
    #pragma unroll
    for (int q = 0; q < 2; q++) {
        const int e0 = (q * 256 + t) * 8;
        uint4 hc = *(const uint4*)(hb + base + e0);
        uint4 uc = *(const uint4*)(ub + base + e0);
        const unsigned int hw[4] = {hc.x, hc.y, hc.z, hc.w};
        const unsigned int uw[4] = {uc.x, uc.y, uc.z, uc.w};
        #pragma unroll
        for (int i = 0; i < 4; i++) {
            float h0 = bf2f(hw[i] & 0xFFFFu), h1 = bf2f(hw[i] >> 16);
            float u0 = bf2f(uw[i] & 0xFFFFu), u1 = bf2f(uw[i] >> 16);
            hv[q * 8 + 2 * i]     = h0; hv[q * 8 + 2 * i + 1] = h1;
            uv[q * 8 + 2 * i]     = u0; uv[q * 8 + 2 * i + 1] = u1;
            h2 += h0 * h0 + h1 * h1;
            u2 += u0 * u0 + u1 * u1;
            hu += h0 * u0 + h1 * u1;
        }
    }
    #pragma unroll
    for (int o = 32; o > 0; o >>= 1) {
        h2 += __shfl_down(h2, o, 64);
        u2 += __shfl_down(u2, o, 64);
        hu += __shfl_down(hu, o, 64);
    }
    __shared__ float red[3][4];
    const int w = t >> 6;
    if ((t & 63) == 0) { red[0][w] = h2; red[1][w] = u2; red[2][w] = hu; }
    __syncthreads();
    h2 = red[0][0] + red[0][1] + red[0][2] + red[0][3];
    u2 = red[1][0] + red[1][1] + red[1][2] + red[1][3];
    hu = red[2][0] + red[2][1] + red[2][2] + red[2][3];

    const float cc = c[row];
    const float sc = sqrtf(cc);
    float nh = fmaxf(sqrtf(h2), EPSV);
    float nu = fmaxf(sqrtf(u2), EPSV);
    float ah = fminf(fmaxf(sc * nh, EPSV), 1.0f - 1e-5f);
    float au = fminf(fmaxf(sc * nu, EPSV), 1.0f - 1e-5f);
    float ath = 0.5f * log1pf(2.0f * ah / (1.0f - ah));
    float atu = 0.5f * log1pf(2.0f * au / (1.0f - au));
    float alpha = tanhf((1.0f - T_C) * ath) / (sc * nh);
    float beta  = tanhf(T_C * atu) / (sc * nu);
    float x2 = alpha * alpha * h2;
    float y2 = beta * beta * u2;
    float xy = alpha * beta * hu;
    float den = 1.0f + 2.0f * cc * xy + cc * cc * x2 * y2;
    den = fmaxf(den, EPSV);
    float ca = (1.0f + 2.0f * cc * xy + cc * y2) * alpha / den;
    float cb = (1.0f - cc * x2) * beta / den;
    if (isnan(ca) || isnan(cb)) { ca = 1.0f; cb = 0.0f; }

    #pragma unroll
    for (int q = 0; q < 2; q++) {
        const int e0 = (q * 256 + t) * 8;
        unsigned int ow[4];
        #pragma unroll
        for (int i = 0; i < 4; i++) {
            float z0 = ca * hv[q * 8 + 2 * i]     + cb * uv[q * 8 + 2 * i];
            float z1 = ca * hv[q * 8 + 2 * i + 1] + cb * uv[q * 8 + 2 * i + 1];
            ow[i] = (unsigned int)f2bf(z0) | ((unsigned int)f2bf(z1) << 16);
        }
        *(uint4*)(zb + base + e0) = make_uint4(ow[0], ow[1], ow[2], ow[3]);
    }
}

// ---------------------------------------------------------------------------
extern "C" void kernel_launch(void* const* d_in, const int* in_sizes, int n_in,
                              void* d_out, int out_size, void* d_ws, size_t ws_size,
                              hipStream_t stream)
{
    const float* x    = (const float*)d_in[0];
    const float* W1   = (const float*)d_in[1];
    const float* b1   = (const float*)d_in[2];
    const float* W2   = (const float*)d_in[3];
    const float* b2   = (const float*)d_in[4];
    const float* Wout = (const float*)d_in[5];
    const float* bout = (const float*)d_in[6];
    const float* cf   = (const float*)d_in[7];
    const float* cs   = (const float*)d_in[8];
    const float* proj = (const float*)d_in[9];
    float* out = (float*)d_out;

    char* ws = (char*)d_ws;
    unsigned short* x_bf = (unsigned short*)(ws);               // 32 MiB (reused as z_bf)
    unsigned short* w_bf = (unsigned short*)(ws + (33554432));  // 32 MiB (W1T/W2T/WoutT)
    unsigned short* h_bf = (unsigned short*)(ws + (67108864));  // 32 MiB
    unsigned short* u_bf = (unsigned short*)(ws + (100663296)); // 32 MiB
    float* vvec = (float*)(ws + 134217728);                     // 16 KiB
    float* cvec = (float*)(ws + 134217728 + 16384);             // 16 KiB

    // 1. curvature prep + fused cast/row-dot
    proj_cf<<<IND / 256, 256, 0, stream>>>(proj, cf, vvec);
    cast_curv<<<BATCH, 256, 0, stream>>>(x, vvec, cs, x_bf, cvec);

    // 2. h = tanh(x @ W1 + b1)
    transpose_cast64<<<dim3(HIDD / 64, IND / 64), 256, 0, stream>>>(W1, w_bf, IND, HIDD);
    gemm256<0><<<dim3(HIDD / 256, BATCH / 256), 512, 0, stream>>>(x_bf, w_bf, b1, h_bf, HIDD, IND);

    // 3. u = sigmoid(h @ W2 + b2)
    transpose_cast64<<<dim3(HIDD / 64, HIDD / 64), 256, 0, stream>>>(W2, w_bf, HIDD, HIDD);
    gemm256<1><<<dim3(HIDD / 256, BATCH / 256), 512, 0, stream>>>(h_bf, w_bf, b2, u_bf, HIDD, HIDD);

    // 4. z = poincare(h, u, c)   (z overwrites x_bf)
    poincare_kernel<<<BATCH, 256, 0, stream>>>(h_bf, u_bf, cvec, x_bf);

    // 5. out = z @ Wout + bout
    transpose_cast64<<<dim3(OUTD / 64, HIDD / 64), 256, 0, stream>>>(Wout, w_bf, HIDD, OUTD);
    gemm_out128<<<dim3(OUTD / 128, BATCH / 128), 512, 0, stream>>>(x_bf, w_bf, bout, out, OUTD, HIDD);
}

// Round 13
// 380.340 us; speedup vs baseline: 5.9145x; 1.0143x over previous
//
#include <hip/hip_runtime.h>
#include <hip/hip_bf16.h>
#include <math.h>

// ---------------------------------------------------------------------------
// ImprovedDynamicCurvatureMLP on MI355X (gfx950)  -- R12 + triple-buffered out-GEMM
//   x_bf,c = fused cast + per-row curvature
//   h_bf  = gemm256<tanh>(x_bf, W1^T)   [256^2, 8-wave, kk-split, hoisted addr]
//   u_bf  = gemm256<sigmoid>(h_bf, W2^T)
//   z_bf  = a(row)*h + b(row)*u         (Poincare layer = row scalars)
//   out   = gemm_out128(z_bf, Wout^T)   [128^2, 3-buffer 2-tile-ahead pipeline]
// ---------------------------------------------------------------------------

typedef __attribute__((ext_vector_type(8)))  __bf16 bf16x8;
typedef __attribute__((ext_vector_type(4)))  float  f32x4;
typedef __attribute__((ext_vector_type(8)))  unsigned short us8;

constexpr int BATCH = 4096;
constexpr int IND   = 4096;
constexpr int HIDD  = 4096;
constexpr int OUTD  = 1024;
constexpr float T_C  = 0.7f;
constexpr float MINC = 1e-5f;
constexpr float MAXC = 10.0f;
constexpr float EPSV = 1e-7f;

__device__ __forceinline__ float bf2f(unsigned int us) {
    return __uint_as_float(us << 16);
}
__device__ __forceinline__ unsigned short f2bf(float f) {
    unsigned int u = __float_as_uint(f);
    u = (u + 0x7FFFu + ((u >> 16) & 1u)) >> 16;   // round-to-nearest-even
    return (unsigned short)u;
}
__device__ __forceinline__ void stage16(const void* src, const void* dst) {
    __builtin_amdgcn_global_load_lds(
        (const __attribute__((address_space(1))) unsigned int*)src,
        (__attribute__((address_space(3))) unsigned int*)dst, 16, 0, 0);
}

// ------------------------------------------ fused cast f32->bf16 + row dot(x,v)
__global__ __launch_bounds__(256)
void cast_curv(const float* __restrict__ x, const float* __restrict__ v,
               const float* __restrict__ cs,
               unsigned short* __restrict__ xb, float* __restrict__ c)
{
    const int row = blockIdx.x;
    const float* xr = x + (size_t)row * IND;
    unsigned short* ob = xb + (size_t)row * IND;
    float s = 0.f;
    for (int i = threadIdx.x; i < IND / 4; i += 256) {
        float4 w  = ((const float4*)xr)[i];
        float4 vv = ((const float4*)v)[i];
        s += w.x * vv.x + w.y * vv.y + w.z * vv.z + w.w * vv.w;
        ushort4 o;
        o.x = f2bf(w.x); o.y = f2bf(w.y); o.z = f2bf(w.z); o.w = f2bf(w.w);
        ((ushort4*)ob)[i] = o;
    }
    #pragma unroll
    for (int o = 32; o > 0; o >>= 1) s += __shfl_down(s, o, 64);
    __shared__ float red[4];
    if ((threadIdx.x & 63) == 0) red[threadIdx.x >> 6] = s;
    __syncthreads();
    if (threadIdx.x == 0) {
        float tot = red[0] + red[1] + red[2] + red[3];
        float adj = 1.0f / (1.0f + expf(-(tot + cs[0])));
        float cc  = MINC + (MAXC - MINC) * adj;
        c[row] = fminf(fmaxf(cc, MINC), MAXC);
    }
}

// ---------------------- transpose + cast: [K,N]f32 -> [N,K]bf16, 64x64 tiles
__global__ __launch_bounds__(256)
void transpose_cast64(const float* __restrict__ in, unsigned short* __restrict__ out,
                      int K, int N)
{
    __shared__ float tile[64][65];
    const int k0 = blockIdx.y * 64;
    const int n0 = blockIdx.x * 64;
    const int t = threadIdx.x;
    #pragma unroll
    for (int i = 0; i < 4; i++) {
        const int idx = i * 256 + t;
        const int r = idx >> 4, c4 = (idx & 15) * 4;   // 256-B coalesced rows
        float4 v = *(const float4*)(&in[(size_t)(k0 + r) * N + n0 + c4]);
        tile[r][c4 + 0] = v.x; tile[r][c4 + 1] = v.y;
        tile[r][c4 + 2] = v.z; tile[r][c4 + 3] = v.w;
    }
    __syncthreads();
    #pragma unroll
    for (int j = 0; j < 2; j++) {
        const int idx = j * 256 + t;
        const int r = idx >> 3, c8 = (idx & 7) * 8;    // n-row r, k-chunk c8
        us8 o;
        #pragma unroll
        for (int e = 0; e < 8; e++) o[e] = f2bf(tile[c8 + e][r]);
        *(us8*)(&out[(size_t)(n0 + r) * K + k0 + c8]) = o;
    }
}

// ---------------------------------------------------------------- 256^2 GEMM (B^T)
// R6-best (unchanged from R12): kk-split 4-phase with hoisted addresses.
//   p0: (mi0-3,kk0) reads 4B+4A; stage Ah0,Bh0(t+1); 16 MFMA; vmcnt(4); bar
//   p1: (mi4-7,kk0) reads 4A;    stage Bh1,Ah1(t+1); 16 MFMA;            bar
//   p2: (mi0-3,kk1) reads 4B+4A;                     16 MFMA;            bar
//   p3: (mi4-7,kk1) reads 4A;                        16 MFMA; vmcnt(2);  bar
// Swizzle colbyte ^= ((row&7)<<4) both sides. EPI: 0 tanh->bf16, 1 sigmoid->bf16
template<int EPI>
__global__ __launch_bounds__(512, 2)
void gemm256(const unsigned short* __restrict__ A,
             const unsigned short* __restrict__ Bt,
             const float* __restrict__ bias,
             unsigned short* __restrict__ outp,
             int N, int K)
{
    __shared__ unsigned short lds[4 * 256 * 64];    // A[2][256][64] | B[2][256][64]

    const int t = threadIdx.x;
    const int w = t >> 6, l = t & 63;
    const int wr = w >> 2, wc = w & 3;      // wave grid 2 x 4
    const int lr = l & 15, lg = l >> 4;

    // bijective XCD swizzle (nwg = 256)
    const int nwg = gridDim.x * gridDim.y;
    const int bid = blockIdx.y * gridDim.x + blockIdx.x;
    const int q8 = nwg >> 3, r8 = nwg & 7;
    const int xcd = bid & 7, off = bid >> 3;
    const int wgid = (xcd < r8 ? xcd * (q8 + 1) : r8 * (q8 + 1) + (xcd - r8) * q8) + off;
    const int by = wgid / gridDim.x;
    const int bx = wgid % gridDim.x;

    const int row0 = by * 256, col0 = bx * 256;
    const unsigned short* Ab = A  + (size_t)row0 * K;
    const unsigned short* Bb = Bt + (size_t)col0 * K;
    const int NT = K >> 6;

    f32x4 acc[8][4] = {};

    // ---- hoisted staging addresses: src = base + row*K*2 + (cb ^ ((row&7)<<4))
    const int id0 = t, id1 = 512 + t;
    const int r0 = id0 >> 3, r1 = id1 >> 3;            // rows within a 128-half
    const int cb0 = (id0 & 7) * 16, cb1 = (id1 & 7) * 16;
    const int s0 = cb0 ^ ((r0 & 7) << 4), s1 = cb1 ^ ((r1 & 7) << 4);
    const size_t K2 = (size_t)K * 2;
    const char* pA00 = (const char*)Ab + (size_t)r0 * K2 + s0;          // Ah0
    const char* pA01 = (const char*)Ab + (size_t)r1 * K2 + s1;
    const char* pA10 = pA00 + 128 * K2;                                  // Ah1
    const char* pA11 = pA01 + 128 * K2;
    const char* pB00 = (const char*)Bb + (size_t)r0 * K2 + s0;          // Bh0
    const char* pB01 = (const char*)Bb + (size_t)r1 * K2 + s1;
    const char* pB10 = pB00 + 128 * K2;                                  // Bh1
    const char* pB11 = pB01 + 128 * K2;
    // LDS dst element offsets (linear, rule 21): A region [0,32768), B +32768
    const int dA0a = id0 * 8,          dA0b = id1 * 8;
    const int dA1a = 8192 + id0 * 8,   dA1b = 8192 + id1 * 8;
    const int dB0a = 32768 + id0 * 8,  dB0b = 32768 + id1 * 8;
    const int dB1a = 40960 + id0 * 8,  dB1b = 40960 + id1 * 8;

    // ---- hoisted read bases (byte offsets into lds)
    const int sw = (lr & 7) << 4;
    const int c0 = (lg * 16) ^ sw;
    const int c1 = (64 + lg * 16) ^ sw;
    const int aofc0 = (wr * 16 + lr) * 128 + c0;
    const int aofc1 = (wr * 16 + lr) * 128 + c1;
    const int bofc0 = 65536 + (wc * 64 + lr) * 128 + c0;
    const int bofc1 = 65536 + (wc * 64 + lr) * 128 + c1;
    const char* ldsb = (const char*)lds;

    // prologue: tile 0 -> buf 0: Ah0, Bh0, Bh1, Ah1; keep Ah1 (2 loads) in flight
    stage16(pA00, lds + dA0a); stage16(pA01, lds + dA0b);
    stage16(pB00, lds + dB0a); stage16(pB01, lds + dB0b);
    stage16(pB10, lds + dB1a); stage16(pB11, lds + dB1b);
    stage16(pA10, lds + dA1a); stage16(pA11, lds + dA1b);
    asm volatile("s_waitcnt vmcnt(2)" ::: "memory");
    __builtin_amdgcn_s_barrier();

    for (int kt = 0; kt < NT; ++kt) {
        const int buf = kt & 1, nb = buf ^ 1;
        const bool pre = (kt + 1 < NT);
        // advance staging pointers to tile kt+1
        pA00 += 128; pA01 += 128; pA10 += 128; pA11 += 128;
        pB00 += 128; pB01 += 128; pB10 += 128; pB11 += 128;
        const int bufby = buf * 32768;          // read-side byte offset
        const int bsh   = nb * 16384;           // stage-side element offset
        const char* rA0 = ldsb + bufby + aofc0;
        const char* rA1 = ldsb + bufby + aofc1;
        const char* rB0 = ldsb + bufby + bofc0;
        const char* rB1 = ldsb + bufby + bofc1;

        bf16x8 bfk[4], afk[4];

        // -------- p0: (mi0-3, kk0); stage Ah0,Bh0(t+1)
        #pragma unroll
        for (int ni = 0; ni < 4; ni++) bfk[ni] = *(const bf16x8*)(rB0 + ni * 2048);
        #pragma unroll
        for (int mi = 0; mi < 4; mi++) afk[mi] = *(const bf16x8*)(rA0 + mi * 4096);
        if (pre) {
            stage16(pA00, lds + bsh + dA0a); stage16(pA01, lds + bsh + dA0b);
            stage16(pB00, lds + bsh + dB0a); stage16(pB01, lds + bsh + dB0b);
        }
        __builtin_amdgcn_s_setprio(1);
        #pragma unroll
        for (int mi = 0; mi < 4; mi++)
            #pragma unroll
            for (int ni = 0; ni < 4; ni++)
                acc[mi][ni] = __builtin_amdgcn_mfma_f32_16x16x32_bf16(
                    afk[mi], bfk[ni], acc[mi][ni], 0, 0, 0);
        __builtin_amdgcn_s_setprio(0);
        if (pre) asm volatile("s_waitcnt vmcnt(4)" ::: "memory");
        else     asm volatile("s_waitcnt vmcnt(0)" ::: "memory");
        __builtin_amdgcn_s_barrier();

        // -------- p1: (mi4-7, kk0); stage Bh1,Ah1(t+1)
        #pragma unroll
        for (int mi = 0; mi < 4; mi++) afk[mi] = *(const bf16x8*)(rA0 + 16384 + mi * 4096);
        if (pre) {
            stage16(pB10, lds + bsh + dB1a); stage16(pB11, lds + bsh + dB1b);
            stage16(pA10, lds + bsh + dA1a); stage16(pA11, lds + bsh + dA1b);
        }
        __builtin_amdgcn_s_setprio(1);
        #pragma unroll
        for (int mi = 0; mi < 4; mi++)
            #pragma unroll
            for (int ni = 0; ni < 4; ni++)
                acc[4 + mi][ni] = __builtin_amdgcn_mfma_f32_16x16x32_bf16(
                    afk[mi], bfk[ni], acc[4 + mi][ni], 0, 0, 0);
        __builtin_amdgcn_s_setprio(0);
        __builtin_amdgcn_s_barrier();

        // -------- p2: (mi0-3, kk1)
        #pragma unroll
        for (int ni = 0; ni < 4; ni++) bfk[ni] = *(const bf16x8*)(rB1 + ni * 2048);
        #pragma unroll
        for (int mi = 0; mi < 4; mi++) afk[mi] = *(const bf16x8*)(rA1 + mi * 4096);
        __builtin_amdgcn_s_setprio(1);
        #pragma unroll
        for (int mi = 0; mi < 4; mi++)
            #pragma unroll
            for (int ni = 0; ni < 4; ni++)
                acc[mi][ni] = __builtin_amdgcn_mfma_f32_16x16x32_bf16(
                    afk[mi], bfk[ni], acc[mi][ni], 0, 0, 0);
        __builtin_amdgcn_s_setprio(0);
        __builtin_amdgcn_s_barrier();

        // -------- p3: (mi4-7, kk1)
        #pragma unroll
        for (int mi = 0; mi < 4; mi++) afk[mi] = *(const bf16x8*)(rA1 + 16384 + mi * 4096);
        __builtin_amdgcn_s_setprio(1);
        #pragma unroll
        for (int mi = 0; mi < 4; mi++)
            #pragma unroll
            for (int ni = 0; ni < 4; ni++)
                acc[4 + mi][ni] = __builtin_amdgcn_mfma_f32_16x16x32_bf16(
                    afk[mi], bfk[ni], acc[4 + mi][ni], 0, 0, 0);
        __builtin_amdgcn_s_setprio(0);
        if (pre) asm volatile("s_waitcnt vmcnt(2)" ::: "memory");
        else     asm volatile("s_waitcnt vmcnt(0)" ::: "memory");
        __builtin_amdgcn_s_barrier();
    }

    // epilogue: m-frag mi at row wr*16 + mi*32; within frag row = lg*4+r, col = lr
    const int colb = col0 + wc * 64;
    #pragma unroll
    for (int ni = 0; ni < 4; ni++) {
        const int cg = colb + ni * 16 + lr;
        const float bv = bias[cg];
        #pragma unroll
        for (int mi = 0; mi < 8; mi++) {
            #pragma unroll
            for (int r = 0; r < 4; r++) {
                const int rg = row0 + wr * 16 + mi * 32 + lg * 4 + r;
                float v = acc[mi][ni][r] + bv;
                if constexpr (EPI == 0) v = tanhf(v);
                else                    v = 1.0f / (1.0f + expf(-v));
                outp[(size_t)rg * N + cg] = f2bf(v);
            }
        }
    }
}

// ------------------------------------------- 128^2 GEMM (B^T), f32 out, 3-buffer
// BM=BN=128, BK=64, 512 thr = 8 waves (2Mx4N), per-wave 64x32.
// TRIPLE-buffered (96 KiB, free at 1 block/CU): during tile t stage tile t+2
// (p0: kk0 pair, p1: kk1 pair). ONE vmcnt(4)+barrier per tile (retires tile
// t+1's 4 loads, issued 3-4 phases (~1100+cy) earlier -> HBM latency covered;
// tile t+2's 4 loads stay in flight, never drains to 0 mid-loop). No intra-tile
// barrier (reads hit buf, stage hits buf+2: no hazard; buffer (kt+3)%3 == kt%3
// is re-staged only after the kt-end barrier where all waves finished kt reads).
// Swizzle colbyte ^= ((row&3)<<4) both sides (64-B kk-half rows).
__global__ __launch_bounds__(512, 2)
void gemm_out128(const unsigned short* __restrict__ A,
                 const unsigned short* __restrict__ Bt,
                 const float* __restrict__ bias,
                 float* __restrict__ outp,
                 int N, int K)
{
    __shared__ unsigned short lds[49152];   // 96 KiB = 3 bufs x 32 KiB

    const int t = threadIdx.x;
    const int w = t >> 6, l = t & 63;
    const int wr = w >> 2, wc = w & 3;      // wave grid 2 x 4
    const int lr = l & 15, lg = l >> 4;

    const int nwg = gridDim.x * gridDim.y;
    const int bid = blockIdx.y * gridDim.x + blockIdx.x;
    const int q8 = nwg >> 3, r8 = nwg & 7;
    const int xcd = bid & 7, off = bid >> 3;
    const int wgid = (xcd < r8 ? xcd * (q8 + 1) : r8 * (q8 + 1) + (xcd - r8) * q8) + off;
    const int by = wgid / gridDim.x;
    const int bx = wgid % gridDim.x;

    const int row0 = by * 128, col0 = bx * 128;
    const unsigned short* Ab = A  + (size_t)row0 * K;
    const unsigned short* Bb = Bt + (size_t)col0 * K;
    const int NT = K >> 6;

    f32x4 acc[4][2] = {};

    // staging: thread t covers row = t>>2, 16-B chunk (t&3) of a 128x64-B sub-tile
    const int sr = t >> 2;
    const int scb = ((t & 3) * 16) ^ ((sr & 3) << 4);
    const size_t K2 = (size_t)K * 2;
    const char* pAk0 = (const char*)Ab + (size_t)sr * K2 + scb;
    const char* pAk1 = pAk0 + 64;
    const char* pBk0 = (const char*)Bb + (size_t)sr * K2 + scb;
    const char* pBk1 = pBk0 + 64;
    // LDS dst BYTE offsets within one 32-KiB buffer: [Akk0 8K][Akk1 8K][Bkk0 8K][Bkk1 8K]
    const int dAk0 = t * 16,          dAk1 = 8192 + t * 16;
    const int dBk0 = 16384 + t * 16,  dBk1 = 24576 + t * 16;

    // read bases (byte offsets within buffer): row stride 64 B, kk1 = +8192
    const int csw = (lg * 16) ^ ((lr & 3) << 4);
    const int aof = (wr * 64 + lr) * 64 + csw;
    const int bof = 16384 + (wc * 32 + lr) * 64 + csw;
    char* ldsc = (char*)lds;

    // prologue: tile0 -> buf0, tile1 -> buf1; retire tile0 (keep tile1 in flight)
    stage16(pAk0, ldsc + dAk0); stage16(pBk0, ldsc + dBk0);
    stage16(pAk1, ldsc + dAk1); stage16(pBk1, ldsc + dBk1);
    pAk0 += 128; pAk1 += 128; pBk0 += 128; pBk1 += 128;      // -> tile 1
    stage16(pAk0, ldsc + 32768 + dAk0); stage16(pBk0, ldsc + 32768 + dBk0);
    stage16(pAk1, ldsc + 32768 + dAk1); stage16(pBk1, ldsc + 32768 + dBk1);
    asm volatile("s_waitcnt vmcnt(4)" ::: "memory");
    __builtin_amdgcn_s_barrier();

    int buf = 0, sb = 2;
    for (int kt = 0; kt < NT; ++kt) {
        const bool pre2 = (kt + 2 < NT);
        pAk0 += 128; pAk1 += 128; pBk0 += 128; pBk1 += 128;  // -> tile kt+2
        const char* rA0 = ldsc + buf * 32768 + aof;
        const char* rB0 = ldsc + buf * 32768 + bof;
        const char* rA1 = rA0 + 8192;
        const char* rB1 = rB0 + 8192;
        char* sbase = ldsc + sb * 32768;

        bf16x8 af[4], bfr[2];

        // -------- p0: kk0; stage kk0(kt+2)   (no barrier: no intra-tile hazard)
        #pragma unroll
        for (int nj = 0; nj < 2; nj++) bfr[nj] = *(const bf16x8*)(rB0 + nj * 1024);
        #pragma unroll
        for (int mi = 0; mi < 4; mi++) af[mi] = *(const bf16x8*)(rA0 + mi * 1024);
        if (pre2) { stage16(pAk0, sbase + dAk0); stage16(pBk0, sbase + dBk0); }
        __builtin_amdgcn_s_setprio(1);
        #pragma unroll
        for (int mi = 0; mi < 4; mi++)
            #pragma unroll
            for (int nj = 0; nj < 2; nj++)
                acc[mi][nj] = __builtin_amdgcn_mfma_f32_16x16x32_bf16(
                    af[mi], bfr[nj], acc[mi][nj], 0, 0, 0);
        __builtin_amdgcn_s_setprio(0);

        // -------- p1: kk1; stage kk1(kt+2); tile-end wait + barrier
        #pragma unroll
        for (int nj = 0; nj < 2; nj++) bfr[nj] = *(const bf16x8*)(rB1 + nj * 1024);
        #pragma unroll
        for (int mi = 0; mi < 4; mi++) af[mi] = *(const bf16x8*)(rA1 + mi * 1024);
        if (pre2) { stage16(pAk1, sbase + dAk1); stage16(pBk1, sbase + dBk1); }
        __builtin_amdgcn_s_setprio(1);
        #pragma unroll
        for (int mi = 0; mi < 4; mi++)
            #pragma unroll
            for (int nj = 0; nj < 2; nj++)
                acc[mi][nj] = __builtin_amdgcn_mfma_f32_16x16x32_bf16(
                    af[mi], bfr[nj], acc[mi][nj], 0, 0, 0);
        __builtin_amdgcn_s_setprio(0);
        if (kt + 1 < NT) {
            if (pre2) asm volatile("s_waitcnt vmcnt(4)" ::: "memory");
            else      asm volatile("s_waitcnt vmcnt(0)" ::: "memory");
        }
        __builtin_amdgcn_s_barrier();

        buf = (buf == 2) ? 0 : buf + 1;
        sb  = (sb  == 2) ? 0 : sb  + 1;
    }

    // epilogue
    #pragma unroll
    for (int nj = 0; nj < 2; nj++) {
        const int cg = col0 + wc * 32 + nj * 16 + lr;
        const float bv = bias[cg];
        #pragma unroll
        for (int mi = 0; mi < 4; mi++)
            #pragma unroll
            for (int r = 0; r < 4; r++) {
                const int rg = row0 + wr * 64 + mi * 16 + lg * 4 + r;
                outp[(size_t)rg * N + cg] = acc[mi][nj][r] + bv;
            }
    }
}

// ---------------------------------------------------------------- v = proj @ curv_feat
__global__ __launch_bounds__(256)
void proj_cf(const float* __restrict__ proj, const float* __restrict__ cf,
             float* __restrict__ v)
{
    int i = blockIdx.x * 256 + threadIdx.x;
    if (i < IND) {
        float s = 0.f;
        #pragma unroll
        for (int j = 0; j < 16; j++) s += proj[i * 16 + j] * cf[j];
        v[i] = s;
    }
}

// ---------------------------------------------------------------- Poincare layer
__global__ __launch_bounds__(256)
void poincare_kernel(const unsigned short* __restrict__ hb,
                     const unsigned short* __restrict__ ub,
                     const float* __restrict__ c,
                     unsigned short* __restrict__ zb)
{
    const int row = blockIdx.x;
    const int t = threadIdx.x;
    const size_t base = (size_t)row * HIDD;

    float hv[16], uv[16];
    float h2 = 0.f, u2 = 0.f, hu = 0.f;
    #pragma unroll
    for (int q = 0; q < 2; q++) {
        const int e0 = (q * 256 + t) * 8;
        uint4 hc = *(const uint4*)(hb + base + e0);
        uint4 uc = *(const uint4*)(ub + base + e0);
        const unsigned int hw[4] = {hc.x, hc.y, hc.z, hc.w};
        const unsigned int uw[4] = {uc.x, uc.y, uc.z, uc.w};
        #pragma unroll
        for (int i = 0; i < 4; i++) {
            float h0 = bf2f(hw[i] & 0xFFFFu), h1 = bf2f(hw[i] >> 16);
            float u0 = bf2f(uw[i] & 0xFFFFu), u1 = bf2f(uw[i] >> 16);
            hv[q * 8 + 2 * i]     = h0; hv[q * 8 + 2 * i + 1] = h1;
            uv[q * 8 + 2 * i]     = u0; uv[q * 8 + 2 * i + 1] = u1;
            h2 += h0 * h0 + h1 * h1;
            u2 += u0 * u0 + u1 * u1;
            hu += h0 * u0 + h1 * u1;
        }
    }
    #pragma unroll
    for (int o = 32; o > 0; o >>= 1) {
        h2 += __shfl_down(h2, o, 64);
        u2 += __shfl_down(u2, o, 64);
        hu += __shfl_down(hu, o, 64);
    }
    __shared__ float red[3][4];
    const int w = t >> 6;
    if ((t & 63) == 0) { red[0][w] = h2; red[1][w] = u2; red[2][w] = hu; }
    __syncthreads();
    h2 = red[0][0] + red[0][1] + red[0][2] + red[0][3];
    u2 = red[1][0] + red[1][1] + red[1][2] + red[1][3];
    hu = red[2][0] + red[2][1] + red[2][2] + red[2][3];

    const float cc = c[row];
    const float sc = sqrtf(cc);
    float nh = fmaxf(sqrtf(h2), EPSV);
    float nu = fmaxf(sqrtf(u2), EPSV);
    float ah = fminf(fmaxf(sc * nh, EPSV), 1.0f - 1e-5f);
    float au = fminf(fmaxf(sc * nu, EPSV), 1.0f - 1e-5f);
    float ath = 0.5f * log1pf(2.0f * ah / (1.0f - ah));
    float atu = 0.5f * log1pf(2.0f * au / (1.0f - au));
    float alpha = tanhf((1.0f - T_C) * ath) / (sc * nh);
    float beta  = tanhf(T_C * atu) / (sc * nu);
    float x2 = alpha * alpha * h2;
    float y2 = beta * beta * u2;
    float xy = alpha * beta * hu;
    float den = 1.0f + 2.0f * cc * xy + cc * cc * x2 * y2;
    den = fmaxf(den, EPSV);
    float ca = (1.0f + 2.0f * cc * xy + cc * y2) * alpha / den;
    float cb = (1.0f - cc * x2) * beta / den;
    if (isnan(ca) || isnan(cb)) { ca = 1.0f; cb = 0.0f; }

    #pragma unroll
    for (int q = 0; q < 2; q++) {
        const int e0 = (q * 256 + t) * 8;
        unsigned int ow[4];
        #pragma unroll
        for (int i = 0; i < 4; i++) {
            float z0 = ca * hv[q * 8 + 2 * i]     + cb * uv[q * 8 + 2 * i];
            float z1 = ca * hv[q * 8 + 2 * i + 1] + cb * uv[q * 8 + 2 * i + 1];
            ow[i] = (unsigned int)f2bf(z0) | ((unsigned int)f2bf(z1) << 16);
        }
        *(uint4*)(zb + base + e0) = make_uint4(ow[0], ow[1], ow[2], ow[3]);
    }
}

// ---------------------------------------------------------------------------
extern "C" void kernel_launch(void* const* d_in, const int* in_sizes, int n_in,
                              void* d_out, int out_size, void* d_ws, size_t ws_size,
                              hipStream_t stream)
{
    const float* x    = (const float*)d_in[0];
    const float* W1   = (const float*)d_in[1];
    const float* b1   = (const float*)d_in[2];
    const float* W2   = (const float*)d_in[3];
    const float* b2   = (const float*)d_in[4];
    const float* Wout = (const float*)d_in[5];
    const float* bout = (const float*)d_in[6];
    const float* cf   = (const float*)d_in[7];
    const float* cs   = (const float*)d_in[8];
    const float* proj = (const float*)d_in[9];
    float* out = (float*)d_out;

    char* ws = (char*)d_ws;
    unsigned short* x_bf = (unsigned short*)(ws);               // 32 MiB (reused as z_bf)
    unsigned short* w_bf = (unsigned short*)(ws + (33554432));  // 32 MiB (W1T/W2T/WoutT)
    unsigned short* h_bf = (unsigned short*)(ws + (67108864));  // 32 MiB
    unsigned short* u_bf = (unsigned short*)(ws + (100663296)); // 32 MiB
    float* vvec = (float*)(ws + 134217728);                     // 16 KiB
    float* cvec = (float*)(ws + 134217728 + 16384);             // 16 KiB

    // 1. curvature prep + fused cast/row-dot
    proj_cf<<<IND / 256, 256, 0, stream>>>(proj, cf, vvec);
    cast_curv<<<BATCH, 256, 0, stream>>>(x, vvec, cs, x_bf, cvec);

    // 2. h = tanh(x @ W1 + b1)
    transpose_cast64<<<dim3(HIDD / 64, IND / 64), 256, 0, stream>>>(W1, w_bf, IND, HIDD);
    gemm256<0><<<dim3(HIDD / 256, BATCH / 256), 512, 0, stream>>>(x_bf, w_bf, b1, h_bf, HIDD, IND);

    // 3. u = sigmoid(h @ W2 + b2)
    transpose_cast64<<<dim3(HIDD / 64, HIDD / 64), 256, 0, stream>>>(W2, w_bf, HIDD, HIDD);
    gemm256<1><<<dim3(HIDD / 256, BATCH / 256), 512, 0, stream>>>(h_bf, w_bf, b2, u_bf, HIDD, HIDD);

    // 4. z = poincare(h, u, c)   (z overwrites x_bf)
    poincare_kernel<<<BATCH, 256, 0, stream>>>(h_bf, u_bf, cvec, x_bf);

    // 5. out = z @ Wout + bout
    transpose_cast64<<<dim3(OUTD / 64, HIDD / 64), 256, 0, stream>>>(Wout, w_bf, HIDD, OUTD);
    gemm_out128<<<dim3(OUTD / 128, BATCH / 128), 512, 0, stream>>>(x_bf, w_bf, bout, out, OUTD, HIDD);
}